// Round 4
// baseline (344.273 us; speedup 1.0000x reference)
//
#include <hip/hip_runtime.h>
#include <math.h>

#define TEMP_F   0.5f
#define ALPHA_F  1.0f
#define BETA_F   5.5f
#define GAMMA_F  5.0f
#define N_IMG    400
#define D_DIM    512
#define C_CLS    1000
#define C_PAD    1024
#define M_SUP    16000
#define LIST_CAP 96

typedef __attribute__((ext_vector_type(8))) short short8;
typedef __attribute__((ext_vector_type(4))) float f32x4;

// ---------- helpers ----------
__device__ __forceinline__ short f2bf(float f) {
    unsigned u = __float_as_uint(f);
    unsigned r = (u + 0x7fffu + ((u >> 16) & 1u)) >> 16;
    return (short)r;
}
__device__ __forceinline__ float bf2f(short s) {
    return __uint_as_float(((unsigned)(unsigned short)s) << 16);
}
__device__ __forceinline__ unsigned encf(float f) {
    unsigned u = __float_as_uint(f);
    return (u & 0x80000000u) ? ~u : (u | 0x80000000u);
}
__device__ __forceinline__ float decf(unsigned u) {
    return (u & 0x80000000u) ? __uint_as_float(u & 0x7FFFFFFFu) : __uint_as_float(~u);
}

__device__ __forceinline__ float block_reduce_sum(float v) {
    __shared__ float red[4];
    #pragma unroll
    for (int o = 32; o > 0; o >>= 1) v += __shfl_down(v, o, 64);
    int w = threadIdx.x >> 6, l = threadIdx.x & 63;
    __syncthreads();
    if (l == 0) red[w] = v;
    __syncthreads();
    float r = red[0];
    int nw = blockDim.x >> 6;
    for (int i = 1; i < nw; ++i) r += red[i];
    return r;
}

__device__ __forceinline__ float block_reduce_max(float v) {
    __shared__ float redm[4];
    #pragma unroll
    for (int o = 32; o > 0; o >>= 1) v = fmaxf(v, __shfl_down(v, o, 64));
    int w = threadIdx.x >> 6, l = threadIdx.x & 63;
    __syncthreads();
    if (l == 0) redm[w] = v;
    __syncthreads();
    float r = redm[0];
    int nw = blockDim.x >> 6;
    for (int i = 1; i < nw; ++i) r = fmaxf(r, redm[i]);
    return r;
}

__device__ __forceinline__ void gload_lds16(const void* g, void* l) {
    __builtin_amdgcn_global_load_lds(
        (const __attribute__((address_space(1))) unsigned int*)g,
        (__attribute__((address_space(3))) unsigned int*)l, 16, 0, 0);
}

// ---------- kernels ----------
__global__ void init_mm_k(unsigned* mm) {
    mm[0] = encf(INFINITY);   // klmin
    mm[1] = encf(-INFINITY);  // klmax
    mm[2] = encf(INFINITY);   // nkmin
    mm[3] = encf(-INFINITY);  // nkmax
}

__global__ void normalize_rows_k(const float* __restrict__ src, short* __restrict__ dst) {
    int row = blockIdx.x;
    const float* s = src + (long)row * D_DIM;
    short* d = dst + (long)row * D_DIM;
    float ss = 0.f;
    for (int c = threadIdx.x; c < D_DIM; c += blockDim.x) { float v = s[c]; ss += v * v; }
    float tot = block_reduce_sum(ss);
    float inv = 1.0f / fmaxf(sqrtf(tot), 1e-12f);
    for (int c = threadIdx.x; c < D_DIM; c += blockDim.x) d[c] = f2bf(s[c] * inv);
}

// S [D_DIM x M_SUP] fp32 -> Sb [M_SUP x D_DIM] bf16
__global__ void transpose_bf16_k(const float* __restrict__ S, short* __restrict__ Sb) {
    __shared__ float tile[32][33];
    int m0 = blockIdx.x * 32, d0 = blockIdx.y * 32;
    int tx = threadIdx.x & 31, ty = threadIdx.x >> 5;  // 32 x 8
    #pragma unroll
    for (int r = 0; r < 32; r += 8)
        tile[ty + r][tx] = S[(long)(d0 + ty + r) * M_SUP + m0 + tx];
    __syncthreads();
    #pragma unroll
    for (int r = 0; r < 32; r += 8)
        Sb[(long)(m0 + ty + r) * D_DIM + d0 + tx] = f2bf(tile[tx][ty + r]);
}

// 128x128 bf16 MFMA GEMM. EPI: 0 = fp32 store, 1 = bf16 store.
template<int EPI>
__global__ __launch_bounds__(256) void mfma_gemm(
    const short* __restrict__ A, const short* __restrict__ B, void* __restrict__ Cm,
    int I, int Jclamp, int Jout, int K, long lda, long ldb, long ldc, float alpha)
{
    __shared__ short As[128 * 32];
    __shared__ short Bs[128 * 32];
    const int tid = threadIdx.x;
    const int wave = tid >> 6;
    const int lane = tid & 63;
    const int i0 = blockIdx.y * 128;
    const int j0 = blockIdx.x * 128;

    const int srow = wave * 16 + (lane >> 2);
    const int skk  = (lane & 3) * 8;

    const int wm = (wave & 1) * 64;
    const int wn = (wave >> 1) * 64;
    const int fr = lane & 15;
    const int fq = lane >> 4;

    f32x4 acc[4][4] = {};

    for (int k0 = 0; k0 < K; k0 += 32) {
        #pragma unroll
        for (int q = 0; q < 2; ++q) {
            int gi = i0 + q * 64 + srow; if (gi > I - 1) gi = I - 1;
            gload_lds16(A + (long)gi * lda + k0 + skk, As + q * 2048 + wave * 512);
        }
        #pragma unroll
        for (int q = 0; q < 2; ++q) {
            int gj = j0 + q * 64 + srow; if (gj > Jclamp - 1) gj = Jclamp - 1;
            gload_lds16(B + (long)gj * ldb + k0 + skk, Bs + q * 2048 + wave * 512);
        }
        __syncthreads();

        short8 af[4], bf[4];
        #pragma unroll
        for (int mi = 0; mi < 4; ++mi)
            af[mi] = *(const short8*)(As + (wm + mi * 16 + fr) * 32 + fq * 8);
        #pragma unroll
        for (int ni = 0; ni < 4; ++ni)
            bf[ni] = *(const short8*)(Bs + (wn + ni * 16 + fr) * 32 + fq * 8);
        #pragma unroll
        for (int mi = 0; mi < 4; ++mi)
            #pragma unroll
            for (int ni = 0; ni < 4; ++ni)
                acc[mi][ni] = __builtin_amdgcn_mfma_f32_16x16x32_bf16(
                    af[mi], bf[ni], acc[mi][ni], 0, 0, 0);
        __syncthreads();
    }

    #pragma unroll
    for (int mi = 0; mi < 4; ++mi) {
        #pragma unroll
        for (int ni = 0; ni < 4; ++ni) {
            int gj = j0 + wn + ni * 16 + fr;
            if (gj >= Jout) continue;
            #pragma unroll
            for (int t = 0; t < 4; ++t) {
                int gi = i0 + wm + mi * 16 + fq * 4 + t;
                if (gi < I) {
                    float v = alpha * acc[mi][ni][t];
                    if (EPI == 1) ((short*)Cm)[(long)gi * ldc + gj] = f2bf(v);
                    else          ((float*)Cm)[(long)gi * ldc + gj] = v;
                }
            }
        }
    }
}

// 64x128 bf16 MFMA GEMM for skinny-I cases.
// EPI 2: kl = ent[i] - acc + lse[j]; minmax -> mm[0..1]; NO store.
// EPI 3: store bf16 nk [i][16000]; minmax of acc -> mm[2..3].
template<int EPI>
__global__ __launch_bounds__(256) void gemm64(
    const short* __restrict__ A, const short* __restrict__ B, short* __restrict__ Cm,
    int I, int K, long lda, long ldb,
    const float* __restrict__ ent, const float* __restrict__ lse, unsigned* __restrict__ mm)
{
    __shared__ short As[64 * 32];
    __shared__ short Bs[128 * 32];
    const int tid = threadIdx.x;
    const int wave = tid >> 6;
    const int lane = tid & 63;
    const int i0 = blockIdx.y * 64;
    const int j0 = blockIdx.x * 128;

    const int srow = wave * 16 + (lane >> 2);
    const int skk  = (lane & 3) * 8;
    const int fr = lane & 15;
    const int fq = lane >> 4;
    const int wn = wave * 32;

    f32x4 acc[4][2] = {};

    for (int k0 = 0; k0 < K; k0 += 32) {
        {
            int gi = i0 + srow; if (gi > I - 1) gi = I - 1;
            gload_lds16(A + (long)gi * lda + k0 + skk, As + wave * 512);
        }
        #pragma unroll
        for (int q = 0; q < 2; ++q) {
            int gj = j0 + q * 64 + srow;
            gload_lds16(B + (long)gj * ldb + k0 + skk, Bs + q * 2048 + wave * 512);
        }
        __syncthreads();

        short8 af[4], bf[2];
        #pragma unroll
        for (int mi = 0; mi < 4; ++mi)
            af[mi] = *(const short8*)(As + (mi * 16 + fr) * 32 + fq * 8);
        #pragma unroll
        for (int ni = 0; ni < 2; ++ni)
            bf[ni] = *(const short8*)(Bs + (wn + ni * 16 + fr) * 32 + fq * 8);
        #pragma unroll
        for (int mi = 0; mi < 4; ++mi)
            #pragma unroll
            for (int ni = 0; ni < 2; ++ni)
                acc[mi][ni] = __builtin_amdgcn_mfma_f32_16x16x32_bf16(
                    af[mi], bf[ni], acc[mi][ni], 0, 0, 0);
        __syncthreads();
    }

    float lmin = INFINITY, lmax = -INFINITY;

    #pragma unroll
    for (int ni = 0; ni < 2; ++ni) {
        int gj = j0 + wn + ni * 16 + fr;
        float lsev = (EPI == 2) ? lse[gj] : 0.f;
        #pragma unroll
        for (int mi = 0; mi < 4; ++mi) {
            #pragma unroll
            for (int t = 0; t < 4; ++t) {
                int gi = i0 + mi * 16 + fq * 4 + t;
                float v = acc[mi][ni][t];
                if (EPI == 2) {
                    int gic = gi < I ? gi : (I - 1);
                    v = ent[gic] - v + lsev;
                }
                lmin = fminf(lmin, v);
                lmax = fmaxf(lmax, v);
                if (EPI == 3 && gi < I)
                    Cm[(long)gi * M_SUP + gj] = f2bf(v);
            }
        }
    }

    #pragma unroll
    for (int o = 32; o > 0; o >>= 1) {
        lmin = fminf(lmin, __shfl_down(lmin, o, 64));
        lmax = fmaxf(lmax, __shfl_down(lmax, o, 64));
    }
    __shared__ float rmin[4], rmax[4];
    if (lane == 0) { rmin[wave] = lmin; rmax[wave] = lmax; }
    __syncthreads();
    if (tid == 0) {
        float bmin = fminf(fminf(rmin[0], rmin[1]), fminf(rmin[2], rmin[3]));
        float bmax = fmaxf(fmaxf(rmax[0], rmax[1]), fmaxf(rmax[2], rmax[3]));
        int base = (EPI == 2) ? 0 : 2;
        atomicMin(&mm[base + 0], encf(bmin));
        atomicMax(&mm[base + 1], encf(bmax));
    }
}

// per-row logsumexp over tb bf16 [M_SUP x C_PAD], valid cols < C_CLS
__global__ __launch_bounds__(256) void row_lse_k(const short* __restrict__ t, float* __restrict__ lse) {
    int row = blockIdx.x;
    const short* r = t + (long)row * C_PAD;
    int c = threadIdx.x * 4;
    int2 w = *(const int2*)(r + c);
    float v0 = bf2f((short)(w.x & 0xffff)), v1 = bf2f((short)(w.x >> 16));
    float v2 = bf2f((short)(w.y & 0xffff)), v3 = bf2f((short)(w.y >> 16));
    bool b0 = c + 0 < C_CLS, b1 = c + 1 < C_CLS, b2 = c + 2 < C_CLS, b3 = c + 3 < C_CLS;
    float mx = -INFINITY;
    if (b0) mx = fmaxf(mx, v0);
    if (b1) mx = fmaxf(mx, v1);
    if (b2) mx = fmaxf(mx, v2);
    if (b3) mx = fmaxf(mx, v3);
    mx = block_reduce_max(mx);
    float se = 0.f;
    if (b0) se += __expf(v0 - mx);
    if (b1) se += __expf(v1 - mx);
    if (b2) se += __expf(v2 - mx);
    if (b3) se += __expf(v3 - mx);
    se = block_reduce_sum(se);
    if (threadIdx.x == 0) lse[row] = mx + logf(se);
}

// test softmax: logits = 2*dot; writes p bf16 (pad zero) and entropy
__global__ void test_softmax_k(const float* __restrict__ dot, short* __restrict__ p,
                               float* __restrict__ ent) {
    int n = blockIdx.x;
    const float* dr = dot + (long)n * C_PAD;
    short* pr = p + (long)n * C_PAD;
    float mx = -INFINITY;
    for (int c = threadIdx.x; c < C_CLS; c += blockDim.x) mx = fmaxf(mx, 2.f * dr[c]);
    mx = block_reduce_max(mx);
    float se = 0.f;
    for (int c = threadIdx.x; c < C_CLS; c += blockDim.x) se += __expf(2.f * dr[c] - mx);
    se = block_reduce_sum(se);
    float logsum = mx + logf(se);
    float e = 0.f;
    for (int c = threadIdx.x; c < C_PAD; c += blockDim.x) {
        if (c < C_CLS) {
            float lp = 2.f * dr[c] - logsum;
            float pv = __expf(lp);
            pr[c] = f2bf(pv);
            e += pv * lp;
        } else {
            pr[c] = 0;
        }
    }
    e = block_reduce_sum(e);
    if (threadIdx.x == 0) ent[n] = e;
}

// per-class: Tagg[c,:] = sum_{m: label=c} tb[m,:]; LS[c]; cnt[c]
__global__ __launch_bounds__(256) void tagg_k(
    const short* __restrict__ tb, const int* __restrict__ labels,
    const float* __restrict__ lse, short* __restrict__ Taggb,
    float* __restrict__ cntf, float* __restrict__ LS)
{
    int c = blockIdx.x;
    int tid = threadIdx.x;
    __shared__ int list[LIST_CAP];
    __shared__ int lcount;
    if (tid == 0) lcount = 0;
    __syncthreads();
    for (int m = tid; m < M_SUP; m += 256)
        if (labels[m] == c) {
            int p = atomicAdd(&lcount, 1);
            if (p < LIST_CAP) list[p] = m;
        }
    __syncthreads();
    int n = lcount < LIST_CAP ? lcount : LIST_CAP;
    int col = tid * 4;
    float a0 = 0.f, a1 = 0.f, a2 = 0.f, a3 = 0.f;
    for (int i = 0; i < n; ++i) {
        int2 w = *(const int2*)(tb + (long)list[i] * C_PAD + col);
        a0 += bf2f((short)(w.x & 0xffff));
        a1 += bf2f((short)(w.x >> 16));
        a2 += bf2f((short)(w.y & 0xffff));
        a3 += bf2f((short)(w.y >> 16));
    }
    short* o = Taggb + (long)c * C_PAD + col;
    o[0] = f2bf(a0); o[1] = f2bf(a1); o[2] = f2bf(a2); o[3] = f2bf(a3);
    if (tid == 0) {
        float s = 0.f;
        for (int i = 0; i < n; ++i) s += lse[list[i]];
        LS[c] = s;
        cntf[c] = (float)lcount;
    }
}

// out[n,c] = 100*dot - GAMMA*((KLS - cnt*klmin)*ratio + cnt*nkmin)
// KLS = cnt*ent[n] - pTagg[n,c] + LS[c]
__global__ __launch_bounds__(256) void out_init_k(
    const float* __restrict__ dot, const float* __restrict__ pTagg,
    const float* __restrict__ ent, const float* __restrict__ cntf,
    const float* __restrict__ LS, const unsigned* __restrict__ mm,
    float* __restrict__ out)
{
    int n = blockIdx.x;
    float klmin = decf(mm[0]), klmax = decf(mm[1]);
    float nkmin = decf(mm[2]), nkmax = decf(mm[3]);
    float ratio = (nkmax - nkmin) / (klmax - klmin);
    float e = ent[n];
    for (int c = threadIdx.x; c < C_CLS; c += 256) {
        float cc = cntf[c];
        float kls = cc * e - pTagg[(long)n * C_PAD + c] + LS[c];
        float v = 100.f * dot[(long)n * C_PAD + c]
                - GAMMA_F * ((kls - cc * klmin) * ratio + cc * nkmin);
        out[(long)n * C_CLS + c] = v;
    }
}

// out[n,c] += ALPHA * sum_{m in chunk, label=c} exp(BETA*(nk-1))
__global__ __launch_bounds__(256) void sexp_k(
    const short* __restrict__ nkb, const int* __restrict__ labels, float* __restrict__ out)
{
    int n = blockIdx.y;
    int m0 = blockIdx.x * 4000;
    int tid = threadIdx.x;
    __shared__ float bins[C_CLS];
    for (int c = tid; c < C_CLS; c += 256) bins[c] = 0.f;
    __syncthreads();
    for (int m = m0 + tid; m < m0 + 4000; m += 256) {
        float v = bf2f(nkb[(long)n * M_SUP + m]);
        atomicAdd(&bins[labels[m]], __expf(BETA_F * (v - 1.f)));
    }
    __syncthreads();
    for (int c = tid; c < C_CLS; c += 256)
        atomicAdd(&out[(long)n * C_CLS + c], ALPHA_F * bins[c]);
}

// ---------- launch ----------
extern "C" void kernel_launch(void* const* d_in, const int* in_sizes, int n_in,
                              void* d_out, int out_size, void* d_ws, size_t ws_size,
                              hipStream_t stream) {
    const float* image_features = (const float*)d_in[0];   // [N, D]
    const float* text_embeds    = (const float*)d_in[1];   // [C, D]
    const float* support_feats  = (const float*)d_in[2];   // [D, M]
    const int*   support_labels = (const int*)d_in[3];     // [M]
    float* out = (float*)d_out;

    char* base = (char*)d_ws;
    size_t off = 0;
    auto alloc = [&](size_t bytes) {
        void* p = base + off;
        off = (off + bytes + 255) & ~(size_t)255;
        return p;
    };
    short* Tnb   = (short*)alloc(sizeof(short) * C_CLS * D_DIM);
    short* imgb  = (short*)alloc(sizeof(short) * N_IMG * D_DIM);
    short* Sb    = (short*)alloc(sizeof(short) * M_SUP * D_DIM);
    short* tb    = (short*)alloc(sizeof(short) * M_SUP * C_PAD);
    short* pb    = (short*)alloc(sizeof(short) * N_IMG * C_PAD);
    short* nkb   = (short*)alloc(sizeof(short) * N_IMG * M_SUP);
    short* Taggb = (short*)alloc(sizeof(short) * C_CLS * C_PAD);
    float* dot   = (float*)alloc(sizeof(float) * N_IMG * C_PAD);
    float* pTagg = (float*)alloc(sizeof(float) * N_IMG * C_PAD);
    float* lse   = (float*)alloc(sizeof(float) * M_SUP);
    float* ent   = (float*)alloc(sizeof(float) * N_IMG);
    float* cntf  = (float*)alloc(sizeof(float) * C_CLS);
    float* LS    = (float*)alloc(sizeof(float) * C_CLS);
    unsigned* mm = (unsigned*)alloc(256);

    init_mm_k<<<1, 1, 0, stream>>>(mm);
    normalize_rows_k<<<C_CLS, 256, 0, stream>>>(text_embeds, Tnb);
    normalize_rows_k<<<N_IMG, 256, 0, stream>>>(image_features, imgb);
    transpose_bf16_k<<<dim3(M_SUP / 32, D_DIM / 32), 256, 0, stream>>>(support_feats, Sb);

    // GEMM1: tb[m,c] = 2 * Sb[m,:] . Tnb[c,:]
    mfma_gemm<1><<<dim3(8, 125), 256, 0, stream>>>(
        Sb, Tnb, tb, M_SUP, C_CLS, C_PAD, D_DIM, D_DIM, D_DIM, C_PAD, 2.0f);

    row_lse_k<<<M_SUP, 256, 0, stream>>>(tb, lse);

    // GEMM0: dot[n,c] = imgb[n,:] . Tnb[c,:]
    mfma_gemm<0><<<dim3(8, 4), 256, 0, stream>>>(
        imgb, Tnb, dot, N_IMG, C_CLS, C_PAD, D_DIM, D_DIM, D_DIM, C_PAD, 1.0f);

    test_softmax_k<<<N_IMG, 256, 0, stream>>>(dot, pb, ent);

    // Tagg[c,:] = sum_{label=c} tb[m,:]; LS, cnt
    tagg_k<<<C_CLS, 256, 0, stream>>>(tb, support_labels, lse, Taggb, cntf, LS);

    // pTagg[n,c] = pb[n,:] . Taggb[c,:]
    mfma_gemm<0><<<dim3(8, 4), 256, 0, stream>>>(
        pb, Taggb, pTagg, N_IMG, C_CLS, C_CLS, C_PAD, C_PAD, C_PAD, C_PAD, 1.0f);

    // GEMM2': kl minmax only (no store)
    gemm64<2><<<dim3(125, 7), 256, 0, stream>>>(
        pb, tb, nullptr, N_IMG, C_PAD, C_PAD, C_PAD, ent, lse, mm);

    // GEMM3': nk bf16 store + minmax
    gemm64<3><<<dim3(125, 7), 256, 0, stream>>>(
        imgb, Sb, nkb, N_IMG, D_DIM, D_DIM, D_DIM, nullptr, nullptr, mm);

    out_init_k<<<N_IMG, 256, 0, stream>>>(dot, pTagg, ent, cntf, LS, mm, out);

    sexp_k<<<dim3(4, N_IMG), 256, 0, stream>>>(nkb, support_labels, out);
}

// Round 5
// 329.390 us; speedup vs baseline: 1.0452x; 1.0452x over previous
//
#include <hip/hip_runtime.h>
#include <math.h>

#define TEMP_F   0.5f
#define ALPHA_F  1.0f
#define BETA_F   5.5f
#define GAMMA_F  5.0f
#define N_IMG    400
#define N_PAD    448
#define D_DIM    512
#define C_CLS    1000
#define C_PAD    1024
#define M_SUP    16000
#define LIST_CAP 96

typedef __attribute__((ext_vector_type(8))) short short8;
typedef __attribute__((ext_vector_type(4))) short short4_t;
typedef __attribute__((ext_vector_type(4))) float f32x4;

// ---------- helpers ----------
__device__ __forceinline__ short f2bf(float f) {
    unsigned u = __float_as_uint(f);
    unsigned r = (u + 0x7fffu + ((u >> 16) & 1u)) >> 16;
    return (short)r;
}
__device__ __forceinline__ float bf2f(short s) {
    return __uint_as_float(((unsigned)(unsigned short)s) << 16);
}
__device__ __forceinline__ unsigned encf(float f) {
    unsigned u = __float_as_uint(f);
    return (u & 0x80000000u) ? ~u : (u | 0x80000000u);
}
__device__ __forceinline__ float decf(unsigned u) {
    return (u & 0x80000000u) ? __uint_as_float(u & 0x7FFFFFFFu) : __uint_as_float(~u);
}

__device__ __forceinline__ float block_reduce_sum(float v) {
    __shared__ float red[4];
    #pragma unroll
    for (int o = 32; o > 0; o >>= 1) v += __shfl_down(v, o, 64);
    int w = threadIdx.x >> 6, l = threadIdx.x & 63;
    __syncthreads();
    if (l == 0) red[w] = v;
    __syncthreads();
    float r = red[0];
    int nw = blockDim.x >> 6;
    for (int i = 1; i < nw; ++i) r += red[i];
    return r;
}

__device__ __forceinline__ float block_reduce_max(float v) {
    __shared__ float redm[4];
    #pragma unroll
    for (int o = 32; o > 0; o >>= 1) v = fmaxf(v, __shfl_down(v, o, 64));
    int w = threadIdx.x >> 6, l = threadIdx.x & 63;
    __syncthreads();
    if (l == 0) redm[w] = v;
    __syncthreads();
    float r = redm[0];
    int nw = blockDim.x >> 6;
    for (int i = 1; i < nw; ++i) r = fmaxf(r, redm[i]);
    return r;
}

__device__ __forceinline__ void gload_lds16(const void* g, void* l) {
    __builtin_amdgcn_global_load_lds(
        (const __attribute__((address_space(1))) unsigned int*)g,
        (__attribute__((address_space(3))) unsigned int*)l, 16, 0, 0);
}

// ---------- kernels ----------
__global__ void init_mm_k(unsigned* mm) {
    mm[0] = encf(INFINITY);   // klmin
    mm[1] = encf(-INFINITY);  // klmax
    mm[2] = encf(INFINITY);   // nkmin
    mm[3] = encf(-INFINITY);  // nkmax
}

__global__ void normalize_rows_k(const float* __restrict__ src, short* __restrict__ dst) {
    int row = blockIdx.x;
    const float* s = src + (long)row * D_DIM;
    short* d = dst + (long)row * D_DIM;
    float ss = 0.f;
    for (int c = threadIdx.x; c < D_DIM; c += blockDim.x) { float v = s[c]; ss += v * v; }
    float tot = block_reduce_sum(ss);
    float inv = 1.0f / fmaxf(sqrtf(tot), 1e-12f);
    for (int c = threadIdx.x; c < D_DIM; c += blockDim.x) d[c] = f2bf(s[c] * inv);
}

// S [D_DIM x M_SUP] fp32 -> Sb [M_SUP x D_DIM] bf16
__global__ void transpose_bf16_k(const float* __restrict__ S, short* __restrict__ Sb) {
    __shared__ float tile[32][33];
    int m0 = blockIdx.x * 32, d0 = blockIdx.y * 32;
    int tx = threadIdx.x & 31, ty = threadIdx.x >> 5;  // 32 x 8
    #pragma unroll
    for (int r = 0; r < 32; r += 8)
        tile[ty + r][tx] = S[(long)(d0 + ty + r) * M_SUP + m0 + tx];
    __syncthreads();
    #pragma unroll
    for (int r = 0; r < 32; r += 8)
        Sb[(long)(m0 + ty + r) * D_DIM + d0 + tx] = f2bf(tile[tx][ty + r]);
}

// 128x128 bf16 MFMA GEMM. EPI: 0 = fp32 store, 1 = bf16 store.
template<int EPI>
__global__ __launch_bounds__(256) void mfma_gemm(
    const short* __restrict__ A, const short* __restrict__ B, void* __restrict__ Cm,
    int I, int Jclamp, int Jout, int K, long lda, long ldb, long ldc, float alpha)
{
    __shared__ short As[128 * 32];
    __shared__ short Bs[128 * 32];
    const int tid = threadIdx.x;
    const int wave = tid >> 6;
    const int lane = tid & 63;
    const int i0 = blockIdx.y * 128;
    const int j0 = blockIdx.x * 128;

    const int srow = wave * 16 + (lane >> 2);
    const int skk  = (lane & 3) * 8;

    const int wm = (wave & 1) * 64;
    const int wn = (wave >> 1) * 64;
    const int fr = lane & 15;
    const int fq = lane >> 4;

    f32x4 acc[4][4] = {};

    for (int k0 = 0; k0 < K; k0 += 32) {
        #pragma unroll
        for (int q = 0; q < 2; ++q) {
            int gi = i0 + q * 64 + srow; if (gi > I - 1) gi = I - 1;
            gload_lds16(A + (long)gi * lda + k0 + skk, As + q * 2048 + wave * 512);
        }
        #pragma unroll
        for (int q = 0; q < 2; ++q) {
            int gj = j0 + q * 64 + srow; if (gj > Jclamp - 1) gj = Jclamp - 1;
            gload_lds16(B + (long)gj * ldb + k0 + skk, Bs + q * 2048 + wave * 512);
        }
        __syncthreads();

        short8 af[4], bf[4];
        #pragma unroll
        for (int mi = 0; mi < 4; ++mi)
            af[mi] = *(const short8*)(As + (wm + mi * 16 + fr) * 32 + fq * 8);
        #pragma unroll
        for (int ni = 0; ni < 4; ++ni)
            bf[ni] = *(const short8*)(Bs + (wn + ni * 16 + fr) * 32 + fq * 8);
        #pragma unroll
        for (int mi = 0; mi < 4; ++mi)
            #pragma unroll
            for (int ni = 0; ni < 4; ++ni)
                acc[mi][ni] = __builtin_amdgcn_mfma_f32_16x16x32_bf16(
                    af[mi], bf[ni], acc[mi][ni], 0, 0, 0);
        __syncthreads();
    }

    #pragma unroll
    for (int mi = 0; mi < 4; ++mi) {
        #pragma unroll
        for (int ni = 0; ni < 4; ++ni) {
            int gj = j0 + wn + ni * 16 + fr;
            if (gj >= Jout) continue;
            #pragma unroll
            for (int t = 0; t < 4; ++t) {
                int gi = i0 + wm + mi * 16 + fq * 4 + t;
                if (gi < I) {
                    float v = alpha * acc[mi][ni][t];
                    if (EPI == 1) ((short*)Cm)[(long)gi * ldc + gj] = f2bf(v);
                    else          ((float*)Cm)[(long)gi * ldc + gj] = v;
                }
            }
        }
    }
}

// Tall GEMM: I rows (I%64==0, big operand A read ONCE) x 448 cols (all of N).
// Tile 64 x 448; 4 waves, each 64 rows x 112 cols (4 i-frags x 7 j-frags).
// B is [400 x K] (row clamp to 399 for cols 400..447).
// EPI 2: kl[i,j] = ent[j] - acc + lse[i]; minmax -> mm[0..1]; no store.
// EPI 3: store bf16 C[j * M_SUP + i] (transposed, [N x M] layout); minmax -> mm[2..3].
template<int EPI>
__global__ __launch_bounds__(256) void tallgemm(
    const short* __restrict__ A, const short* __restrict__ B, short* __restrict__ Cm,
    int I, int K,
    const float* __restrict__ ent, const float* __restrict__ lse, unsigned* __restrict__ mm)
{
    __shared__ short L[512 * 32];   // rows 0..63 = A, 64..511 = B
    const int tid = threadIdx.x;
    const int wave = tid >> 6;
    const int lane = tid & 63;
    const int i0 = blockIdx.x * 64;
    const int lrow = wave * 16 + (lane >> 2);  // row within a 64-row staging group
    const int seg = lane & 3;

    const int fr = lane & 15;
    const int fq = lane >> 4;
    const int jw = wave * 112;

    f32x4 acc[4][7] = {};

    for (int k0 = 0; k0 < K; k0 += 32) {
        #pragma unroll
        for (int q = 0; q < 8; ++q) {
            int r = q * 64 + lrow;                 // absolute LDS row 0..511
            int g = (seg + (r >> 1)) & 3;          // swizzled global k-segment
            const short* src;
            if (q == 0) {
                src = A + (long)(i0 + r) * K + k0 + g * 8;
            } else {
                int br = r - 64; if (br > N_IMG - 1) br = N_IMG - 1;
                src = B + (long)br * K + k0 + g * 8;
            }
            gload_lds16(src, L + (q * 64 + wave * 16) * 32);
        }
        __syncthreads();

        short8 af[4], bf[7];
        #pragma unroll
        for (int mi = 0; mi < 4; ++mi) {
            int r = mi * 16 + fr;
            int s = (fq - (r >> 1)) & 3;
            af[mi] = *(const short8*)(L + r * 32 + s * 8);
        }
        #pragma unroll
        for (int ni = 0; ni < 7; ++ni) {
            int r = 64 + jw + ni * 16 + fr;
            int s = (fq - (r >> 1)) & 3;
            bf[ni] = *(const short8*)(L + r * 32 + s * 8);
        }
        #pragma unroll
        for (int mi = 0; mi < 4; ++mi)
            #pragma unroll
            for (int ni = 0; ni < 7; ++ni)
                acc[mi][ni] = __builtin_amdgcn_mfma_f32_16x16x32_bf16(
                    af[mi], bf[ni], acc[mi][ni], 0, 0, 0);
        __syncthreads();
    }

    float lmin = INFINITY, lmax = -INFINITY;

    #pragma unroll
    for (int ni = 0; ni < 7; ++ni) {
        int gj = jw + ni * 16 + fr;
        float entv = 0.f;
        if (EPI == 2) entv = ent[gj < N_IMG ? gj : (N_IMG - 1)];
        #pragma unroll
        for (int mi = 0; mi < 4; ++mi) {
            int gi0 = i0 + mi * 16 + fq * 4;
            if (EPI == 2) {
                #pragma unroll
                for (int t = 0; t < 4; ++t) {
                    float v = entv - acc[mi][ni][t] + lse[gi0 + t];
                    lmin = fminf(lmin, v);
                    lmax = fmaxf(lmax, v);
                }
            } else {
                short4_t pk;
                #pragma unroll
                for (int t = 0; t < 4; ++t) {
                    float v = acc[mi][ni][t];
                    lmin = fminf(lmin, v);
                    lmax = fmaxf(lmax, v);
                    pk[t] = f2bf(v);
                }
                if (gj < N_IMG)
                    *(short4_t*)(Cm + (long)gj * M_SUP + gi0) = pk;
            }
        }
    }

    #pragma unroll
    for (int o = 32; o > 0; o >>= 1) {
        lmin = fminf(lmin, __shfl_down(lmin, o, 64));
        lmax = fmaxf(lmax, __shfl_down(lmax, o, 64));
    }
    __shared__ float rmin[4], rmax[4];
    if (lane == 0) { rmin[wave] = lmin; rmax[wave] = lmax; }
    __syncthreads();
    if (tid == 0) {
        float bmin = fminf(fminf(rmin[0], rmin[1]), fminf(rmin[2], rmin[3]));
        float bmax = fmaxf(fmaxf(rmax[0], rmax[1]), fmaxf(rmax[2], rmax[3]));
        int bse = (EPI == 2) ? 0 : 2;
        atomicMin(&mm[bse + 0], encf(bmin));
        atomicMax(&mm[bse + 1], encf(bmax));
    }
}

// per-row logsumexp over tb bf16 [M_SUP x C_PAD], valid cols < C_CLS
__global__ __launch_bounds__(256) void row_lse_k(const short* __restrict__ t, float* __restrict__ lse) {
    int row = blockIdx.x;
    const short* r = t + (long)row * C_PAD;
    int c = threadIdx.x * 4;
    int2 w = *(const int2*)(r + c);
    float v0 = bf2f((short)(w.x & 0xffff)), v1 = bf2f((short)(w.x >> 16));
    float v2 = bf2f((short)(w.y & 0xffff)), v3 = bf2f((short)(w.y >> 16));
    bool b0 = c + 0 < C_CLS, b1 = c + 1 < C_CLS, b2 = c + 2 < C_CLS, b3 = c + 3 < C_CLS;
    float mx = -INFINITY;
    if (b0) mx = fmaxf(mx, v0);
    if (b1) mx = fmaxf(mx, v1);
    if (b2) mx = fmaxf(mx, v2);
    if (b3) mx = fmaxf(mx, v3);
    mx = block_reduce_max(mx);
    float se = 0.f;
    if (b0) se += __expf(v0 - mx);
    if (b1) se += __expf(v1 - mx);
    if (b2) se += __expf(v2 - mx);
    if (b3) se += __expf(v3 - mx);
    se = block_reduce_sum(se);
    if (threadIdx.x == 0) lse[row] = mx + logf(se);
}

// test softmax: logits = 2*dot; writes p bf16 (pad zero) and entropy
__global__ void test_softmax_k(const float* __restrict__ dot, short* __restrict__ p,
                               float* __restrict__ ent) {
    int n = blockIdx.x;
    const float* dr = dot + (long)n * C_PAD;
    short* pr = p + (long)n * C_PAD;
    float mx = -INFINITY;
    for (int c = threadIdx.x; c < C_CLS; c += blockDim.x) mx = fmaxf(mx, 2.f * dr[c]);
    mx = block_reduce_max(mx);
    float se = 0.f;
    for (int c = threadIdx.x; c < C_CLS; c += blockDim.x) se += __expf(2.f * dr[c] - mx);
    se = block_reduce_sum(se);
    float logsum = mx + logf(se);
    float e = 0.f;
    for (int c = threadIdx.x; c < C_PAD; c += blockDim.x) {
        if (c < C_CLS) {
            float lp = 2.f * dr[c] - logsum;
            float pv = __expf(lp);
            pr[c] = f2bf(pv);
            e += pv * lp;
        } else {
            pr[c] = 0;
        }
    }
    e = block_reduce_sum(e);
    if (threadIdx.x == 0) ent[n] = e;
}

// per-class: Tagg[c,:] = sum_{m: label=c} tb[m,:]; LS[c]; cnt[c]
__global__ __launch_bounds__(256) void tagg_k(
    const short* __restrict__ tb, const int* __restrict__ labels,
    const float* __restrict__ lse, short* __restrict__ Taggb,
    float* __restrict__ cntf, float* __restrict__ LS)
{
    int c = blockIdx.x;
    int tid = threadIdx.x;
    __shared__ int list[LIST_CAP];
    __shared__ int lcount;
    if (tid == 0) lcount = 0;
    __syncthreads();
    for (int m = tid; m < M_SUP; m += 256)
        if (labels[m] == c) {
            int p = atomicAdd(&lcount, 1);
            if (p < LIST_CAP) list[p] = m;
        }
    __syncthreads();
    int n = lcount < LIST_CAP ? lcount : LIST_CAP;
    int col = tid * 4;
    float a0 = 0.f, a1 = 0.f, a2 = 0.f, a3 = 0.f;
    for (int i = 0; i < n; ++i) {
        int2 w = *(const int2*)(tb + (long)list[i] * C_PAD + col);
        a0 += bf2f((short)(w.x & 0xffff));
        a1 += bf2f((short)(w.x >> 16));
        a2 += bf2f((short)(w.y & 0xffff));
        a3 += bf2f((short)(w.y >> 16));
    }
    short* o = Taggb + (long)c * C_PAD + col;
    o[0] = f2bf(a0); o[1] = f2bf(a1); o[2] = f2bf(a2); o[3] = f2bf(a3);
    if (tid == 0) {
        float s = 0.f;
        for (int i = 0; i < n; ++i) s += lse[list[i]];
        LS[c] = s;
        cntf[c] = (float)lcount;
    }
}

// fused epilogue: bins scatter + final combine; no global atomics
__global__ __launch_bounds__(256) void final2_k(
    const short* __restrict__ nkb, const int* __restrict__ labels,
    const float* __restrict__ dot, const float* __restrict__ pTagg,
    const float* __restrict__ ent, const float* __restrict__ cntf,
    const float* __restrict__ LS, const unsigned* __restrict__ mm,
    float* __restrict__ out)
{
    int n = blockIdx.x;
    int tid = threadIdx.x;
    __shared__ float bins[C_CLS];
    for (int c = tid; c < C_CLS; c += 256) bins[c] = 0.f;
    __syncthreads();
    const short* row = nkb + (long)n * M_SUP;
    for (int m = tid * 2; m < M_SUP; m += 512) {
        int w = *(const int*)(row + m);
        float v0 = bf2f((short)(w & 0xffff));
        float v1 = bf2f((short)(w >> 16));
        atomicAdd(&bins[labels[m]],     __expf(BETA_F * (v0 - 1.f)));
        atomicAdd(&bins[labels[m + 1]], __expf(BETA_F * (v1 - 1.f)));
    }
    __syncthreads();
    float klmin = decf(mm[0]), klmax = decf(mm[1]);
    float nkmin = decf(mm[2]), nkmax = decf(mm[3]);
    float ratio = (nkmax - nkmin) / (klmax - klmin);
    float e = ent[n];
    for (int c = tid; c < C_CLS; c += 256) {
        float cc = cntf[c];
        float kls = cc * e - pTagg[(long)n * C_PAD + c] + LS[c];
        out[(long)n * C_CLS + c] = 100.f * dot[(long)n * C_PAD + c]
            - GAMMA_F * ((kls - cc * klmin) * ratio + cc * nkmin)
            + ALPHA_F * bins[c];
    }
}

// ---------- launch ----------
extern "C" void kernel_launch(void* const* d_in, const int* in_sizes, int n_in,
                              void* d_out, int out_size, void* d_ws, size_t ws_size,
                              hipStream_t stream) {
    const float* image_features = (const float*)d_in[0];   // [N, D]
    const float* text_embeds    = (const float*)d_in[1];   // [C, D]
    const float* support_feats  = (const float*)d_in[2];   // [D, M]
    const int*   support_labels = (const int*)d_in[3];     // [M]
    float* out = (float*)d_out;

    char* base = (char*)d_ws;
    size_t off = 0;
    auto alloc = [&](size_t bytes) {
        void* p = base + off;
        off = (off + bytes + 255) & ~(size_t)255;
        return p;
    };
    short* Tnb   = (short*)alloc(sizeof(short) * C_CLS * D_DIM);
    short* imgb  = (short*)alloc(sizeof(short) * N_IMG * D_DIM);
    short* Sb    = (short*)alloc(sizeof(short) * M_SUP * D_DIM);
    short* tb    = (short*)alloc(sizeof(short) * M_SUP * C_PAD);
    short* pb    = (short*)alloc(sizeof(short) * N_IMG * C_PAD);
    short* nkb   = (short*)alloc(sizeof(short) * N_IMG * M_SUP);  // [N x M]
    short* Taggb = (short*)alloc(sizeof(short) * C_CLS * C_PAD);
    float* dot   = (float*)alloc(sizeof(float) * N_IMG * C_PAD);
    float* pTagg = (float*)alloc(sizeof(float) * N_IMG * C_PAD);
    float* lse   = (float*)alloc(sizeof(float) * M_SUP);
    float* ent   = (float*)alloc(sizeof(float) * N_IMG);
    float* cntf  = (float*)alloc(sizeof(float) * C_CLS);
    float* LS    = (float*)alloc(sizeof(float) * C_CLS);
    unsigned* mm = (unsigned*)alloc(256);

    init_mm_k<<<1, 1, 0, stream>>>(mm);
    normalize_rows_k<<<C_CLS, 256, 0, stream>>>(text_embeds, Tnb);
    normalize_rows_k<<<N_IMG, 256, 0, stream>>>(image_features, imgb);
    transpose_bf16_k<<<dim3(M_SUP / 32, D_DIM / 32), 256, 0, stream>>>(support_feats, Sb);

    // GEMM1: tb[m,c] = 2 * Sb[m,:] . Tnb[c,:]  (store full C_PAD; pad cols are
    // finite dups of col 999 so downstream K=1024 GEMMs stay clean)
    mfma_gemm<1><<<dim3(8, 125), 256, 0, stream>>>(
        Sb, Tnb, tb, M_SUP, C_CLS, C_PAD, D_DIM, D_DIM, D_DIM, C_PAD, 2.0f);

    row_lse_k<<<M_SUP, 256, 0, stream>>>(tb, lse);

    // GEMM0: dot[n,c] = imgb[n,:] . Tnb[c,:]
    mfma_gemm<0><<<dim3(8, 4), 256, 0, stream>>>(
        imgb, Tnb, dot, N_IMG, C_CLS, C_PAD, D_DIM, D_DIM, D_DIM, C_PAD, 1.0f);

    test_softmax_k<<<N_IMG, 256, 0, stream>>>(dot, pb, ent);

    // Tagg[c,:] = sum_{label=c} tb[m,:]; LS, cnt
    tagg_k<<<C_CLS, 256, 0, stream>>>(tb, support_labels, lse, Taggb, cntf, LS);

    // pTagg[n,c] = pb[n,:] . Taggb[c,:]
    mfma_gemm<0><<<dim3(8, 4), 256, 0, stream>>>(
        pb, Taggb, pTagg, N_IMG, C_CLS, C_CLS, C_PAD, C_PAD, C_PAD, C_PAD, 1.0f);

    // GEMM2': kl minmax only — tb read once (i = M rows)
    tallgemm<2><<<M_SUP / 64, 256, 0, stream>>>(
        tb, pb, nullptr, M_SUP, C_PAD, ent, lse, mm);

    // GEMM3': nk^T store into [N x M] bf16 + minmax — Sb read once
    tallgemm<3><<<M_SUP / 64, 256, 0, stream>>>(
        Sb, imgb, nkb, M_SUP, D_DIM, nullptr, nullptr, mm);

    final2_k<<<N_IMG, 256, 0, stream>>>(
        nkb, support_labels, dot, pTagg, ent, cntf, LS, mm, out);
}

// Round 6
// 317.916 us; speedup vs baseline: 1.0829x; 1.0361x over previous
//
#include <hip/hip_runtime.h>
#include <math.h>

#define TEMP_F   0.5f
#define ALPHA_F  1.0f
#define BETA_F   5.5f
#define GAMMA_F  5.0f
#define N_IMG    400
#define N_PAD    512
#define D_DIM    512
#define C_CLS    1000
#define C_PAD    1024
#define M_SUP    16000
#define LIST_CAP 96

typedef __attribute__((ext_vector_type(8))) short short8;
typedef __attribute__((ext_vector_type(4))) short short4_t;
typedef __attribute__((ext_vector_type(4))) float f32x4;

// ---------- helpers ----------
__device__ __forceinline__ short f2bf(float f) {
    unsigned u = __float_as_uint(f);
    unsigned r = (u + 0x7fffu + ((u >> 16) & 1u)) >> 16;
    return (short)r;
}
__device__ __forceinline__ float bf2f(short s) {
    return __uint_as_float(((unsigned)(unsigned short)s) << 16);
}
__device__ __forceinline__ unsigned encf(float f) {
    unsigned u = __float_as_uint(f);
    return (u & 0x80000000u) ? ~u : (u | 0x80000000u);
}
__device__ __forceinline__ float decf(unsigned u) {
    return (u & 0x80000000u) ? __uint_as_float(u & 0x7FFFFFFFu) : __uint_as_float(~u);
}

__device__ __forceinline__ float block_reduce_sum(float v) {
    __shared__ float red[4];
    #pragma unroll
    for (int o = 32; o > 0; o >>= 1) v += __shfl_down(v, o, 64);
    int w = threadIdx.x >> 6, l = threadIdx.x & 63;
    __syncthreads();
    if (l == 0) red[w] = v;
    __syncthreads();
    float r = red[0];
    int nw = blockDim.x >> 6;
    for (int i = 1; i < nw; ++i) r += red[i];
    return r;
}

__device__ __forceinline__ float block_reduce_max(float v) {
    __shared__ float redm[4];
    #pragma unroll
    for (int o = 32; o > 0; o >>= 1) v = fmaxf(v, __shfl_down(v, o, 64));
    int w = threadIdx.x >> 6, l = threadIdx.x & 63;
    __syncthreads();
    if (l == 0) redm[w] = v;
    __syncthreads();
    float r = redm[0];
    int nw = blockDim.x >> 6;
    for (int i = 1; i < nw; ++i) r = fmaxf(r, redm[i]);
    return r;
}

__device__ __forceinline__ void gload_lds16(const void* g, void* l) {
    __builtin_amdgcn_global_load_lds(
        (const __attribute__((address_space(1))) unsigned int*)g,
        (__attribute__((address_space(3))) unsigned int*)l, 16, 0, 0);
}

// ---------- kernels ----------
__global__ void init_mm_k(unsigned* mm, int* cnt) {
    int t = threadIdx.x;
    if (t == 0) {
        mm[0] = encf(INFINITY);   // klmin
        mm[1] = encf(-INFINITY);  // klmax
        mm[2] = encf(INFINITY);   // nkmin
        mm[3] = encf(-INFINITY);  // nkmax
    }
    for (int c = t; c < C_CLS; c += blockDim.x) cnt[c] = 0;
}

__global__ void normalize_rows_k(const float* __restrict__ src, short* __restrict__ dst) {
    int row = blockIdx.x;
    const float* s = src + (long)row * D_DIM;
    short* d = dst + (long)row * D_DIM;
    float ss = 0.f;
    for (int c = threadIdx.x; c < D_DIM; c += blockDim.x) { float v = s[c]; ss += v * v; }
    float tot = block_reduce_sum(ss);
    float inv = 1.0f / fmaxf(sqrtf(tot), 1e-12f);
    for (int c = threadIdx.x; c < D_DIM; c += blockDim.x) d[c] = f2bf(s[c] * inv);
}

// S [D_DIM x M_SUP] fp32 -> Sb [M_SUP x D_DIM] bf16
__global__ void transpose_bf16_k(const float* __restrict__ S, short* __restrict__ Sb) {
    __shared__ float tile[32][33];
    int m0 = blockIdx.x * 32, d0 = blockIdx.y * 32;
    int tx = threadIdx.x & 31, ty = threadIdx.x >> 5;  // 32 x 8
    #pragma unroll
    for (int r = 0; r < 32; r += 8)
        tile[ty + r][tx] = S[(long)(d0 + ty + r) * M_SUP + m0 + tx];
    __syncthreads();
    #pragma unroll
    for (int r = 0; r < 32; r += 8)
        Sb[(long)(m0 + ty + r) * D_DIM + d0 + tx] = f2bf(tile[tx][ty + r]);
}

// 128x128 bf16 MFMA GEMM. EPI: 0 = fp32 store, 1 = bf16 store.
template<int EPI>
__global__ __launch_bounds__(256) void mfma_gemm(
    const short* __restrict__ A, const short* __restrict__ B, void* __restrict__ Cm,
    int I, int Jclamp, int Jout, int K, long lda, long ldb, long ldc, float alpha)
{
    __shared__ short As[128 * 32];
    __shared__ short Bs[128 * 32];
    const int tid = threadIdx.x;
    const int wave = tid >> 6;
    const int lane = tid & 63;
    const int i0 = blockIdx.y * 128;
    const int j0 = blockIdx.x * 128;

    const int srow = wave * 16 + (lane >> 2);
    const int skk  = (lane & 3) * 8;

    const int wm = (wave & 1) * 64;
    const int wn = (wave >> 1) * 64;
    const int fr = lane & 15;
    const int fq = lane >> 4;

    f32x4 acc[4][4] = {};

    for (int k0 = 0; k0 < K; k0 += 32) {
        #pragma unroll
        for (int q = 0; q < 2; ++q) {
            int gi = i0 + q * 64 + srow; if (gi > I - 1) gi = I - 1;
            gload_lds16(A + (long)gi * lda + k0 + skk, As + q * 2048 + wave * 512);
        }
        #pragma unroll
        for (int q = 0; q < 2; ++q) {
            int gj = j0 + q * 64 + srow; if (gj > Jclamp - 1) gj = Jclamp - 1;
            gload_lds16(B + (long)gj * ldb + k0 + skk, Bs + q * 2048 + wave * 512);
        }
        __syncthreads();

        short8 af[4], bf[4];
        #pragma unroll
        for (int mi = 0; mi < 4; ++mi)
            af[mi] = *(const short8*)(As + (wm + mi * 16 + fr) * 32 + fq * 8);
        #pragma unroll
        for (int ni = 0; ni < 4; ++ni)
            bf[ni] = *(const short8*)(Bs + (wn + ni * 16 + fr) * 32 + fq * 8);
        #pragma unroll
        for (int mi = 0; mi < 4; ++mi)
            #pragma unroll
            for (int ni = 0; ni < 4; ++ni)
                acc[mi][ni] = __builtin_amdgcn_mfma_f32_16x16x32_bf16(
                    af[mi], bf[ni], acc[mi][ni], 0, 0, 0);
        __syncthreads();
    }

    #pragma unroll
    for (int mi = 0; mi < 4; ++mi) {
        #pragma unroll
        for (int ni = 0; ni < 4; ++ni) {
            int gj = j0 + wn + ni * 16 + fr;
            if (gj >= Jout) continue;
            #pragma unroll
            for (int t = 0; t < 4; ++t) {
                int gi = i0 + wm + mi * 16 + fq * 4 + t;
                if (gi < I) {
                    float v = alpha * acc[mi][ni][t];
                    if (EPI == 1) ((short*)Cm)[(long)gi * ldc + gj] = f2bf(v);
                    else          ((float*)Cm)[(long)gi * ldc + gj] = v;
                }
            }
        }
    }
}

// Tall GEMM v2: 64 A-rows x 256 B-cols per block; grid (I/64, 2) covers 512 cols.
// A read at most 2x (once per j-half); B rows clamped to N_IMG-1.
// EPI 2: kl[i,j] = ent[j] - acc + lse[i]; minmax -> mm[0..1]; no store.
// EPI 3: store bf16 C[j * M_SUP + i] ([N x M] layout); minmax -> mm[2..3].
template<int EPI>
__global__ __launch_bounds__(256) void tallgemm(
    const short* __restrict__ A, const short* __restrict__ B, short* __restrict__ Cm,
    int K,
    const float* __restrict__ ent, const float* __restrict__ lse, unsigned* __restrict__ mm)
{
    __shared__ short L[320 * 32];   // rows 0..63 = A-tile, 64..319 = 256 B-rows
    const int tid = threadIdx.x;
    const int wave = tid >> 6;
    const int lane = tid & 63;
    const int i0 = blockIdx.x * 64;
    const int j0 = blockIdx.y * 256;
    const int lrow = lane >> 2;   // 0..15 within a 16-row staging group
    const int seg = lane & 3;

    const int fr = lane & 15;
    const int fq = lane >> 4;
    const int jw = wave * 64;

    f32x4 acc[4][4] = {};

    for (int k0 = 0; k0 < K; k0 += 32) {
        // A: 64 rows, 1 instr/wave
        {
            int r = wave * 16 + lrow;
            int g = (seg + (r >> 1)) & 3;
            gload_lds16(A + (long)(i0 + r) * K + k0 + g * 8, L + (wave * 16) * 32);
        }
        // B: 256 rows, 4 instrs/wave
        #pragma unroll
        for (int q = 0; q < 4; ++q) {
            int r = 64 + q * 64 + wave * 16 + lrow;        // LDS row
            int br = j0 + q * 64 + wave * 16 + lrow;       // global B row
            if (br > N_IMG - 1) br = N_IMG - 1;
            int g = (seg + (r >> 1)) & 3;
            gload_lds16(B + (long)br * K + k0 + g * 8, L + (64 + q * 64 + wave * 16) * 32);
        }
        __syncthreads();

        short8 af[4], bf[4];
        #pragma unroll
        for (int mi = 0; mi < 4; ++mi) {
            int r = mi * 16 + fr;
            int s = (fq - (r >> 1)) & 3;
            af[mi] = *(const short8*)(L + r * 32 + s * 8);
        }
        #pragma unroll
        for (int ni = 0; ni < 4; ++ni) {
            int r = 64 + jw + ni * 16 + fr;
            int s = (fq - (r >> 1)) & 3;
            bf[ni] = *(const short8*)(L + r * 32 + s * 8);
        }
        #pragma unroll
        for (int mi = 0; mi < 4; ++mi)
            #pragma unroll
            for (int ni = 0; ni < 4; ++ni)
                acc[mi][ni] = __builtin_amdgcn_mfma_f32_16x16x32_bf16(
                    af[mi], bf[ni], acc[mi][ni], 0, 0, 0);
        __syncthreads();
    }

    float lmin = INFINITY, lmax = -INFINITY;

    #pragma unroll
    for (int ni = 0; ni < 4; ++ni) {
        int gj = j0 + jw + ni * 16 + fr;
        float entv = 0.f;
        if (EPI == 2) entv = ent[gj < N_IMG ? gj : (N_IMG - 1)];
        #pragma unroll
        for (int mi = 0; mi < 4; ++mi) {
            int gi0 = i0 + mi * 16 + fq * 4;
            if (EPI == 2) {
                #pragma unroll
                for (int t = 0; t < 4; ++t) {
                    float v = entv - acc[mi][ni][t] + lse[gi0 + t];
                    lmin = fminf(lmin, v);
                    lmax = fmaxf(lmax, v);
                }
            } else {
                short4_t pk;
                #pragma unroll
                for (int t = 0; t < 4; ++t) {
                    float v = acc[mi][ni][t];
                    lmin = fminf(lmin, v);
                    lmax = fmaxf(lmax, v);
                    pk[t] = f2bf(v);
                }
                if (gj < N_IMG)
                    *(short4_t*)(Cm + (long)gj * M_SUP + gi0) = pk;
            }
        }
    }

    #pragma unroll
    for (int o = 32; o > 0; o >>= 1) {
        lmin = fminf(lmin, __shfl_down(lmin, o, 64));
        lmax = fmaxf(lmax, __shfl_down(lmax, o, 64));
    }
    __shared__ float rmin[4], rmax[4];
    if (lane == 0) { rmin[wave] = lmin; rmax[wave] = lmax; }
    __syncthreads();
    if (tid == 0) {
        float bmin = fminf(fminf(rmin[0], rmin[1]), fminf(rmin[2], rmin[3]));
        float bmax = fmaxf(fmaxf(rmax[0], rmax[1]), fmaxf(rmax[2], rmax[3]));
        int bse = (EPI == 2) ? 0 : 2;
        atomicMin(&mm[bse + 0], encf(bmin));
        atomicMax(&mm[bse + 1], encf(bmax));
    }
}

// per-row logsumexp over tb bf16 [M_SUP x C_PAD], valid cols < C_CLS
__global__ __launch_bounds__(256) void row_lse_k(const short* __restrict__ t, float* __restrict__ lse) {
    int row = blockIdx.x;
    const short* r = t + (long)row * C_PAD;
    int c = threadIdx.x * 4;
    int2 w = *(const int2*)(r + c);
    float v0 = bf2f((short)(w.x & 0xffff)), v1 = bf2f((short)(w.x >> 16));
    float v2 = bf2f((short)(w.y & 0xffff)), v3 = bf2f((short)(w.y >> 16));
    bool b0 = c + 0 < C_CLS, b1 = c + 1 < C_CLS, b2 = c + 2 < C_CLS, b3 = c + 3 < C_CLS;
    float mx = -INFINITY;
    if (b0) mx = fmaxf(mx, v0);
    if (b1) mx = fmaxf(mx, v1);
    if (b2) mx = fmaxf(mx, v2);
    if (b3) mx = fmaxf(mx, v3);
    mx = block_reduce_max(mx);
    float se = 0.f;
    if (b0) se += __expf(v0 - mx);
    if (b1) se += __expf(v1 - mx);
    if (b2) se += __expf(v2 - mx);
    if (b3) se += __expf(v3 - mx);
    se = block_reduce_sum(se);
    if (threadIdx.x == 0) lse[row] = mx + logf(se);
}

// test softmax: logits = 2*dot; writes p bf16 (pad zero) and entropy
__global__ void test_softmax_k(const float* __restrict__ dot, short* __restrict__ p,
                               float* __restrict__ ent) {
    int n = blockIdx.x;
    const float* dr = dot + (long)n * C_PAD;
    short* pr = p + (long)n * C_PAD;
    float mx = -INFINITY;
    for (int c = threadIdx.x; c < C_CLS; c += blockDim.x) mx = fmaxf(mx, 2.f * dr[c]);
    mx = block_reduce_max(mx);
    float se = 0.f;
    for (int c = threadIdx.x; c < C_CLS; c += blockDim.x) se += __expf(2.f * dr[c] - mx);
    se = block_reduce_sum(se);
    float logsum = mx + logf(se);
    float e = 0.f;
    for (int c = threadIdx.x; c < C_PAD; c += blockDim.x) {
        if (c < C_CLS) {
            float lp = 2.f * dr[c] - logsum;
            float pv = __expf(lp);
            pr[c] = f2bf(pv);
            e += pv * lp;
        } else {
            pr[c] = 0;
        }
    }
    e = block_reduce_sum(e);
    if (threadIdx.x == 0) ent[n] = e;
}

// scatter support indices into per-class lists
__global__ void bucket_k(const int* __restrict__ labels, int* __restrict__ cnt,
                         int* __restrict__ lists) {
    int m = blockIdx.x * 256 + threadIdx.x;
    if (m < M_SUP) {
        int c = labels[m];
        int p = atomicAdd(&cnt[c], 1);
        if (p < LIST_CAP) lists[c * LIST_CAP + p] = m;
    }
}

// per-class: Tagg[c,:] = sum over list; LS[c]; cnt float
__global__ __launch_bounds__(256) void tagg_k(
    const short* __restrict__ tb, const int* __restrict__ cnt,
    const int* __restrict__ lists, const float* __restrict__ lse,
    short* __restrict__ Taggb, float* __restrict__ cntf, float* __restrict__ LS)
{
    int c = blockIdx.x;
    int tid = threadIdx.x;
    int lc = cnt[c];
    int n = lc < LIST_CAP ? lc : LIST_CAP;
    const int* list = lists + (long)c * LIST_CAP;
    int col = tid * 4;
    float a0 = 0.f, a1 = 0.f, a2 = 0.f, a3 = 0.f;
    for (int i = 0; i < n; ++i) {
        int2 w = *(const int2*)(tb + (long)list[i] * C_PAD + col);
        a0 += bf2f((short)(w.x & 0xffff));
        a1 += bf2f((short)(w.x >> 16));
        a2 += bf2f((short)(w.y & 0xffff));
        a3 += bf2f((short)(w.y >> 16));
    }
    short* o = Taggb + (long)c * C_PAD + col;
    o[0] = f2bf(a0); o[1] = f2bf(a1); o[2] = f2bf(a2); o[3] = f2bf(a3);
    if (tid == 0) {
        float s = 0.f;
        for (int i = 0; i < n; ++i) s += lse[list[i]];
        LS[c] = s;
        cntf[c] = (float)lc;
    }
}

// fused epilogue: bins scatter + final combine; 1024 threads for latency hiding
__global__ __launch_bounds__(1024) void final2_k(
    const short* __restrict__ nkb, const int* __restrict__ labels,
    const float* __restrict__ dot, const float* __restrict__ pTagg,
    const float* __restrict__ ent, const float* __restrict__ cntf,
    const float* __restrict__ LS, const unsigned* __restrict__ mm,
    float* __restrict__ out)
{
    int n = blockIdx.x;
    int tid = threadIdx.x;
    __shared__ float bins[C_CLS];
    for (int c = tid; c < C_CLS; c += 1024) bins[c] = 0.f;
    __syncthreads();
    const short* row = nkb + (long)n * M_SUP;
    for (int m = tid * 2; m < M_SUP; m += 2048) {
        int w = *(const int*)(row + m);
        float v0 = bf2f((short)(w & 0xffff));
        float v1 = bf2f((short)(w >> 16));
        atomicAdd(&bins[labels[m]],     __expf(BETA_F * (v0 - 1.f)));
        atomicAdd(&bins[labels[m + 1]], __expf(BETA_F * (v1 - 1.f)));
    }
    __syncthreads();
    float klmin = decf(mm[0]), klmax = decf(mm[1]);
    float nkmin = decf(mm[2]), nkmax = decf(mm[3]);
    float ratio = (nkmax - nkmin) / (klmax - klmin);
    float e = ent[n];
    for (int c = tid; c < C_CLS; c += 1024) {
        float cc = cntf[c];
        float kls = cc * e - pTagg[(long)n * C_PAD + c] + LS[c];
        out[(long)n * C_CLS + c] = 100.f * dot[(long)n * C_PAD + c]
            - GAMMA_F * ((kls - cc * klmin) * ratio + cc * nkmin)
            + ALPHA_F * bins[c];
    }
}

// ---------- launch ----------
extern "C" void kernel_launch(void* const* d_in, const int* in_sizes, int n_in,
                              void* d_out, int out_size, void* d_ws, size_t ws_size,
                              hipStream_t stream) {
    const float* image_features = (const float*)d_in[0];   // [N, D]
    const float* text_embeds    = (const float*)d_in[1];   // [C, D]
    const float* support_feats  = (const float*)d_in[2];   // [D, M]
    const int*   support_labels = (const int*)d_in[3];     // [M]
    float* out = (float*)d_out;

    char* base = (char*)d_ws;
    size_t off = 0;
    auto alloc = [&](size_t bytes) {
        void* p = base + off;
        off = (off + bytes + 255) & ~(size_t)255;
        return p;
    };
    short* Tnb   = (short*)alloc(sizeof(short) * C_CLS * D_DIM);
    short* imgb  = (short*)alloc(sizeof(short) * N_IMG * D_DIM);
    short* Sb    = (short*)alloc(sizeof(short) * M_SUP * D_DIM);
    short* tb    = (short*)alloc(sizeof(short) * M_SUP * C_PAD);
    short* pb    = (short*)alloc(sizeof(short) * N_IMG * C_PAD);
    short* nkb   = (short*)alloc(sizeof(short) * N_IMG * M_SUP);  // [N x M]
    short* Taggb = (short*)alloc(sizeof(short) * C_CLS * C_PAD);
    float* dot   = (float*)alloc(sizeof(float) * N_IMG * C_PAD);
    float* pTagg = (float*)alloc(sizeof(float) * N_IMG * C_PAD);
    float* lse   = (float*)alloc(sizeof(float) * M_SUP);
    float* ent   = (float*)alloc(sizeof(float) * N_IMG);
    float* cntf  = (float*)alloc(sizeof(float) * C_CLS);
    float* LS    = (float*)alloc(sizeof(float) * C_CLS);
    int*   cnt   = (int*)alloc(sizeof(int) * C_CLS);
    int*   lists = (int*)alloc(sizeof(int) * C_CLS * LIST_CAP);
    unsigned* mm = (unsigned*)alloc(256);

    init_mm_k<<<1, 256, 0, stream>>>(mm, cnt);
    normalize_rows_k<<<C_CLS, 256, 0, stream>>>(text_embeds, Tnb);
    normalize_rows_k<<<N_IMG, 256, 0, stream>>>(image_features, imgb);
    transpose_bf16_k<<<dim3(M_SUP / 32, D_DIM / 32), 256, 0, stream>>>(support_feats, Sb);
    bucket_k<<<(M_SUP + 255) / 256, 256, 0, stream>>>(support_labels, cnt, lists);

    // GEMM1: tb[m,c] = 2 * Sb[m,:] . Tnb[c,:]  (full C_PAD store; pad cols are
    // finite dups of col 999 so downstream K=1024 GEMMs stay clean)
    mfma_gemm<1><<<dim3(8, 125), 256, 0, stream>>>(
        Sb, Tnb, tb, M_SUP, C_CLS, C_PAD, D_DIM, D_DIM, D_DIM, C_PAD, 2.0f);

    row_lse_k<<<M_SUP, 256, 0, stream>>>(tb, lse);

    // GEMM0: dot[n,c] = imgb[n,:] . Tnb[c,:]
    mfma_gemm<0><<<dim3(8, 4), 256, 0, stream>>>(
        imgb, Tnb, dot, N_IMG, C_CLS, C_PAD, D_DIM, D_DIM, D_DIM, C_PAD, 1.0f);

    test_softmax_k<<<N_IMG, 256, 0, stream>>>(dot, pb, ent);

    // Tagg[c,:] = sum_{label=c} tb[m,:]; LS, cnt
    tagg_k<<<C_CLS, 256, 0, stream>>>(tb, cnt, lists, lse, Taggb, cntf, LS);

    // pTagg[n,c] = pb[n,:] . Taggb[c,:]
    mfma_gemm<0><<<dim3(8, 4), 256, 0, stream>>>(
        pb, Taggb, pTagg, N_IMG, C_CLS, C_CLS, C_PAD, C_PAD, C_PAD, C_PAD, 1.0f);

    // GEMM2': kl minmax only — tb rows on grid.x, j split in 2
    tallgemm<2><<<dim3(M_SUP / 64, 2), 256, 0, stream>>>(
        tb, pb, nullptr, C_PAD, ent, lse, mm);

    // GEMM3': nk^T store into [N x M] bf16 + minmax
    tallgemm<3><<<dim3(M_SUP / 64, 2), 256, 0, stream>>>(
        Sb, imgb, nkb, D_DIM, nullptr, nullptr, mm);

    final2_k<<<N_IMG, 1024, 0, stream>>>(
        nkb, support_labels, dot, pTagg, ent, cntf, LS, mm, out);
}

// Round 7
// 297.225 us; speedup vs baseline: 1.1583x; 1.0696x over previous
//
#include <hip/hip_runtime.h>
#include <math.h>

#define TEMP_F   0.5f
#define ALPHA_F  1.0f
#define BETA_F   5.5f
#define GAMMA_F  5.0f
#define N_IMG    400
#define D_DIM    512
#define C_CLS    1000
#define C_PAD    1024
#define M_SUP    16000
#define LIST_CAP 96

typedef __attribute__((ext_vector_type(8))) short short8;
typedef __attribute__((ext_vector_type(4))) short short4_t;
typedef __attribute__((ext_vector_type(4))) float f32x4;

// ---------- helpers ----------
__device__ __forceinline__ short f2bf(float f) {
    unsigned u = __float_as_uint(f);
    unsigned r = (u + 0x7fffu + ((u >> 16) & 1u)) >> 16;
    return (short)r;
}
__device__ __forceinline__ float bf2f(short s) {
    return __uint_as_float(((unsigned)(unsigned short)s) << 16);
}
__device__ __forceinline__ unsigned encf(float f) {
    unsigned u = __float_as_uint(f);
    return (u & 0x80000000u) ? ~u : (u | 0x80000000u);
}
__device__ __forceinline__ float decf(unsigned u) {
    return (u & 0x80000000u) ? __uint_as_float(u & 0x7FFFFFFFu) : __uint_as_float(~u);
}

__device__ __forceinline__ float block_reduce_sum(float v) {
    __shared__ float red[4];
    #pragma unroll
    for (int o = 32; o > 0; o >>= 1) v += __shfl_down(v, o, 64);
    int w = threadIdx.x >> 6, l = threadIdx.x & 63;
    __syncthreads();
    if (l == 0) red[w] = v;
    __syncthreads();
    float r = red[0];
    int nw = blockDim.x >> 6;
    for (int i = 1; i < nw; ++i) r += red[i];
    return r;
}

__device__ __forceinline__ float block_reduce_max(float v) {
    __shared__ float redm[4];
    #pragma unroll
    for (int o = 32; o > 0; o >>= 1) v = fmaxf(v, __shfl_down(v, o, 64));
    int w = threadIdx.x >> 6, l = threadIdx.x & 63;
    __syncthreads();
    if (l == 0) redm[w] = v;
    __syncthreads();
    float r = redm[0];
    int nw = blockDim.x >> 6;
    for (int i = 1; i < nw; ++i) r = fmaxf(r, redm[i]);
    return r;
}

__device__ __forceinline__ void gload_lds16(const void* g, void* l) {
    __builtin_amdgcn_global_load_lds(
        (const __attribute__((address_space(1))) unsigned int*)g,
        (__attribute__((address_space(3))) unsigned int*)l, 16, 0, 0);
}

// ---------- kernels ----------
__global__ void init_mm_k(unsigned* mm, int* cnt) {
    int t = threadIdx.x;
    if (t == 0) {
        mm[0] = encf(INFINITY);   // klmin
        mm[1] = encf(-INFINITY);  // klmax
        mm[2] = encf(INFINITY);   // nkmin
        mm[3] = encf(-INFINITY);  // nkmax
    }
    for (int c = t; c < C_CLS; c += blockDim.x) cnt[c] = 0;
}

__global__ void normalize_rows_k(const float* __restrict__ src, short* __restrict__ dst) {
    int row = blockIdx.x;
    const float* s = src + (long)row * D_DIM;
    short* d = dst + (long)row * D_DIM;
    float ss = 0.f;
    for (int c = threadIdx.x; c < D_DIM; c += blockDim.x) { float v = s[c]; ss += v * v; }
    float tot = block_reduce_sum(ss);
    float inv = 1.0f / fmaxf(sqrtf(tot), 1e-12f);
    for (int c = threadIdx.x; c < D_DIM; c += blockDim.x) d[c] = f2bf(s[c] * inv);
}

// S [D_DIM x M_SUP] fp32 -> Sb [M_SUP x D_DIM] bf16
__global__ void transpose_bf16_k(const float* __restrict__ S, short* __restrict__ Sb) {
    __shared__ float tile[32][33];
    int m0 = blockIdx.x * 32, d0 = blockIdx.y * 32;
    int tx = threadIdx.x & 31, ty = threadIdx.x >> 5;  // 32 x 8
    #pragma unroll
    for (int r = 0; r < 32; r += 8)
        tile[ty + r][tx] = S[(long)(d0 + ty + r) * M_SUP + m0 + tx];
    __syncthreads();
    #pragma unroll
    for (int r = 0; r < 32; r += 8)
        Sb[(long)(m0 + ty + r) * D_DIM + d0 + tx] = f2bf(tile[tx][ty + r]);
}

// GEMM1 fused: tb[m,c] = 2 * Sb[m,:].Tnb[c,:] (bf16, full C_PAD cols; cols
// >=1000 are dups of col 999) + per-row partial sumexp(t-2) -> atomicAdd lsesum.
// Tile 128 i x 256 j, grid (C_PAD/256, M/128). Swizzled LDS (conflict-free).
__global__ __launch_bounds__(256, 2) void gemm1_k(
    const short* __restrict__ A, const short* __restrict__ B,
    short* __restrict__ tb, float* __restrict__ lsesum)
{
    __shared__ short As[128 * 32];
    __shared__ short Bs[256 * 32];
    const int tid = threadIdx.x;
    const int wave = tid >> 6;
    const int lane = tid & 63;
    const int i0 = blockIdx.y * 128;
    const int j0 = blockIdx.x * 256;
    const int lrow = lane >> 2;
    const int seg = lane & 3;
    const int fr = lane & 15;
    const int fq = lane >> 4;
    const int wm = (wave & 1) * 64;
    const int wn = (wave >> 1) * 128;

    f32x4 acc[4][8] = {};

    for (int k0 = 0; k0 < D_DIM; k0 += 32) {
        #pragma unroll
        for (int q = 0; q < 2; ++q) {
            int r = q * 64 + wave * 16 + lrow;
            int g = (seg + (r >> 1)) & 3;
            gload_lds16(A + (long)(i0 + r) * D_DIM + k0 + g * 8, As + r * 32);
        }
        #pragma unroll
        for (int q = 0; q < 4; ++q) {
            int r = q * 64 + wave * 16 + lrow;
            int br = j0 + r; if (br > C_CLS - 1) br = C_CLS - 1;
            int g = (seg + (r >> 1)) & 3;
            gload_lds16(B + (long)br * D_DIM + k0 + g * 8, Bs + r * 32);
        }
        __syncthreads();

        short8 af[4], bf[8];
        #pragma unroll
        for (int mi = 0; mi < 4; ++mi) {
            int r = wm + mi * 16 + fr;
            int s = (fq - (r >> 1)) & 3;
            af[mi] = *(const short8*)(As + r * 32 + s * 8);
        }
        #pragma unroll
        for (int ni = 0; ni < 8; ++ni) {
            int r = wn + ni * 16 + fr;
            int s = (fq - (r >> 1)) & 3;
            bf[ni] = *(const short8*)(Bs + r * 32 + s * 8);
        }
        #pragma unroll
        for (int mi = 0; mi < 4; ++mi)
            #pragma unroll
            for (int ni = 0; ni < 8; ++ni)
                acc[mi][ni] = __builtin_amdgcn_mfma_f32_16x16x32_bf16(
                    af[mi], bf[ni], acc[mi][ni], 0, 0, 0);
        __syncthreads();
    }

    float rs[4][4];
    #pragma unroll
    for (int mi = 0; mi < 4; ++mi)
        #pragma unroll
        for (int t = 0; t < 4; ++t) rs[mi][t] = 0.f;

    #pragma unroll
    for (int mi = 0; mi < 4; ++mi) {
        #pragma unroll
        for (int ni = 0; ni < 8; ++ni) {
            int gj = j0 + wn + ni * 16 + fr;
            bool valid = gj < C_CLS;
            #pragma unroll
            for (int t = 0; t < 4; ++t) {
                int gi = i0 + wm + mi * 16 + fq * 4 + t;
                short b = f2bf(2.0f * acc[mi][ni][t]);
                tb[(long)gi * C_PAD + gj] = b;
                if (valid) rs[mi][t] += __expf(bf2f(b) - 2.0f);
            }
        }
    }
    // reduce across the 16 lanes of each quad (same rows), then atomic per row
    #pragma unroll
    for (int mi = 0; mi < 4; ++mi) {
        #pragma unroll
        for (int t = 0; t < 4; ++t) {
            float s = rs[mi][t];
            s += __shfl_xor(s, 1, 64);
            s += __shfl_xor(s, 2, 64);
            s += __shfl_xor(s, 4, 64);
            s += __shfl_xor(s, 8, 64);
            if (fr == 0)
                atomicAdd(&lsesum[i0 + wm + mi * 16 + fq * 4 + t], s);
        }
    }
}

__global__ void lse_fin_k(const float* __restrict__ sum, float* __restrict__ lse) {
    int m = blockIdx.x * 256 + threadIdx.x;
    if (m < M_SUP) lse[m] = 2.0f + logf(sum[m]);
}

// 128x128 bf16 MFMA GEMM (swizzled LDS). EPI: 0 = fp32 store, 1 = bf16 store.
template<int EPI>
__global__ __launch_bounds__(256) void mfma_gemm(
    const short* __restrict__ A, const short* __restrict__ B, void* __restrict__ Cm,
    int I, int Jclamp, int Jout, int K, long lda, long ldb, long ldc, float alpha)
{
    __shared__ short As[128 * 32];
    __shared__ short Bs[128 * 32];
    const int tid = threadIdx.x;
    const int wave = tid >> 6;
    const int lane = tid & 63;
    const int i0 = blockIdx.y * 128;
    const int j0 = blockIdx.x * 128;
    const int lrow = lane >> 2;
    const int seg = lane & 3;
    const int wm = (wave & 1) * 64;
    const int wn = (wave >> 1) * 64;
    const int fr = lane & 15;
    const int fq = lane >> 4;

    f32x4 acc[4][4] = {};

    for (int k0 = 0; k0 < K; k0 += 32) {
        #pragma unroll
        for (int q = 0; q < 2; ++q) {
            int r = q * 64 + wave * 16 + lrow;
            int gi = i0 + r; if (gi > I - 1) gi = I - 1;
            int g = (seg + (r >> 1)) & 3;
            gload_lds16(A + (long)gi * lda + k0 + g * 8, As + r * 32);
        }
        #pragma unroll
        for (int q = 0; q < 2; ++q) {
            int r = q * 64 + wave * 16 + lrow;
            int gj = j0 + r; if (gj > Jclamp - 1) gj = Jclamp - 1;
            int g = (seg + (r >> 1)) & 3;
            gload_lds16(B + (long)gj * ldb + k0 + g * 8, Bs + r * 32);
        }
        __syncthreads();

        short8 af[4], bf[4];
        #pragma unroll
        for (int mi = 0; mi < 4; ++mi) {
            int r = wm + mi * 16 + fr;
            int s = (fq - (r >> 1)) & 3;
            af[mi] = *(const short8*)(As + r * 32 + s * 8);
        }
        #pragma unroll
        for (int ni = 0; ni < 4; ++ni) {
            int r = wn + ni * 16 + fr;
            int s = (fq - (r >> 1)) & 3;
            bf[ni] = *(const short8*)(Bs + r * 32 + s * 8);
        }
        #pragma unroll
        for (int mi = 0; mi < 4; ++mi)
            #pragma unroll
            for (int ni = 0; ni < 4; ++ni)
                acc[mi][ni] = __builtin_amdgcn_mfma_f32_16x16x32_bf16(
                    af[mi], bf[ni], acc[mi][ni], 0, 0, 0);
        __syncthreads();
    }

    #pragma unroll
    for (int mi = 0; mi < 4; ++mi) {
        #pragma unroll
        for (int ni = 0; ni < 4; ++ni) {
            int gj = j0 + wn + ni * 16 + fr;
            if (gj >= Jout) continue;
            #pragma unroll
            for (int t = 0; t < 4; ++t) {
                int gi = i0 + wm + mi * 16 + fq * 4 + t;
                if (gi < I) {
                    float v = alpha * acc[mi][ni][t];
                    if (EPI == 1) ((short*)Cm)[(long)gi * ldc + gj] = f2bf(v);
                    else          ((float*)Cm)[(long)gi * ldc + gj] = v;
                }
            }
        }
    }
}

// Tall GEMM: 64 A-rows x 256 B-cols per block; grid (I/64, 2) covers 512 cols.
// EPI 2: kl[i,j] = ent[j] - acc + lse[i]; minmax -> mm[0..1]; no store.
// EPI 3: store bf16 C[j * M_SUP + i] ([N x M] layout); minmax -> mm[2..3].
template<int EPI>
__global__ __launch_bounds__(256) void tallgemm(
    const short* __restrict__ A, const short* __restrict__ B, short* __restrict__ Cm,
    int K,
    const float* __restrict__ ent, const float* __restrict__ lse, unsigned* __restrict__ mm)
{
    __shared__ short L[320 * 32];   // rows 0..63 = A-tile, 64..319 = 256 B-rows
    const int tid = threadIdx.x;
    const int wave = tid >> 6;
    const int lane = tid & 63;
    const int i0 = blockIdx.x * 64;
    const int j0 = blockIdx.y * 256;
    const int lrow = lane >> 2;
    const int seg = lane & 3;

    const int fr = lane & 15;
    const int fq = lane >> 4;
    const int jw = wave * 64;

    f32x4 acc[4][4] = {};

    for (int k0 = 0; k0 < K; k0 += 32) {
        {
            int r = wave * 16 + lrow;
            int g = (seg + (r >> 1)) & 3;
            gload_lds16(A + (long)(i0 + r) * K + k0 + g * 8, L + (wave * 16) * 32);
        }
        #pragma unroll
        for (int q = 0; q < 4; ++q) {
            int r = 64 + q * 64 + wave * 16 + lrow;
            int br = j0 + q * 64 + wave * 16 + lrow;
            if (br > N_IMG - 1) br = N_IMG - 1;
            int g = (seg + (r >> 1)) & 3;
            gload_lds16(B + (long)br * K + k0 + g * 8, L + (64 + q * 64 + wave * 16) * 32);
        }
        __syncthreads();

        short8 af[4], bf[4];
        #pragma unroll
        for (int mi = 0; mi < 4; ++mi) {
            int r = mi * 16 + fr;
            int s = (fq - (r >> 1)) & 3;
            af[mi] = *(const short8*)(L + r * 32 + s * 8);
        }
        #pragma unroll
        for (int ni = 0; ni < 4; ++ni) {
            int r = 64 + jw + ni * 16 + fr;
            int s = (fq - (r >> 1)) & 3;
            bf[ni] = *(const short8*)(L + r * 32 + s * 8);
        }
        #pragma unroll
        for (int mi = 0; mi < 4; ++mi)
            #pragma unroll
            for (int ni = 0; ni < 4; ++ni)
                acc[mi][ni] = __builtin_amdgcn_mfma_f32_16x16x32_bf16(
                    af[mi], bf[ni], acc[mi][ni], 0, 0, 0);
        __syncthreads();
    }

    float lmin = INFINITY, lmax = -INFINITY;

    #pragma unroll
    for (int ni = 0; ni < 4; ++ni) {
        int gj = j0 + jw + ni * 16 + fr;
        float entv = 0.f;
        if (EPI == 2) entv = ent[gj < N_IMG ? gj : (N_IMG - 1)];
        #pragma unroll
        for (int mi = 0; mi < 4; ++mi) {
            int gi0 = i0 + mi * 16 + fq * 4;
            if (EPI == 2) {
                #pragma unroll
                for (int t = 0; t < 4; ++t) {
                    float v = entv - acc[mi][ni][t] + lse[gi0 + t];
                    lmin = fminf(lmin, v);
                    lmax = fmaxf(lmax, v);
                }
            } else {
                short4_t pk;
                #pragma unroll
                for (int t = 0; t < 4; ++t) {
                    float v = acc[mi][ni][t];
                    lmin = fminf(lmin, v);
                    lmax = fmaxf(lmax, v);
                    pk[t] = f2bf(v);
                }
                if (gj < N_IMG)
                    *(short4_t*)(Cm + (long)gj * M_SUP + gi0) = pk;
            }
        }
    }

    #pragma unroll
    for (int o = 32; o > 0; o >>= 1) {
        lmin = fminf(lmin, __shfl_down(lmin, o, 64));
        lmax = fmaxf(lmax, __shfl_down(lmax, o, 64));
    }
    __shared__ float rmin[4], rmax[4];
    if (lane == 0) { rmin[wave] = lmin; rmax[wave] = lmax; }
    __syncthreads();
    if (tid == 0) {
        float bmin = fminf(fminf(rmin[0], rmin[1]), fminf(rmin[2], rmin[3]));
        float bmax = fmaxf(fmaxf(rmax[0], rmax[1]), fmaxf(rmax[2], rmax[3]));
        int bse = (EPI == 2) ? 0 : 2;
        atomicMin(&mm[bse + 0], encf(bmin));
        atomicMax(&mm[bse + 1], encf(bmax));
    }
}

// test softmax: logits = 2*dot; writes p bf16 (pad zero) and entropy
__global__ void test_softmax_k(const float* __restrict__ dot, short* __restrict__ p,
                               float* __restrict__ ent) {
    int n = blockIdx.x;
    const float* dr = dot + (long)n * C_PAD;
    short* pr = p + (long)n * C_PAD;
    float mx = -INFINITY;
    for (int c = threadIdx.x; c < C_CLS; c += blockDim.x) mx = fmaxf(mx, 2.f * dr[c]);
    mx = block_reduce_max(mx);
    float se = 0.f;
    for (int c = threadIdx.x; c < C_CLS; c += blockDim.x) se += __expf(2.f * dr[c] - mx);
    se = block_reduce_sum(se);
    float logsum = mx + logf(se);
    float e = 0.f;
    for (int c = threadIdx.x; c < C_PAD; c += blockDim.x) {
        if (c < C_CLS) {
            float lp = 2.f * dr[c] - logsum;
            float pv = __expf(lp);
            pr[c] = f2bf(pv);
            e += pv * lp;
        } else {
            pr[c] = 0;
        }
    }
    e = block_reduce_sum(e);
    if (threadIdx.x == 0) ent[n] = e;
}

// scatter support indices into per-class lists
__global__ void bucket_k(const int* __restrict__ labels, int* __restrict__ cnt,
                         int* __restrict__ lists) {
    int m = blockIdx.x * 256 + threadIdx.x;
    if (m < M_SUP) {
        int c = labels[m];
        int p = atomicAdd(&cnt[c], 1);
        if (p < LIST_CAP) lists[c * LIST_CAP + p] = m;
    }
}

// per-class: Tagg[c,:] = sum over list; LS[c]; cnt float
__global__ __launch_bounds__(256) void tagg_k(
    const short* __restrict__ tb, const int* __restrict__ cnt,
    const int* __restrict__ lists, const float* __restrict__ lse,
    short* __restrict__ Taggb, float* __restrict__ cntf, float* __restrict__ LS)
{
    int c = blockIdx.x;
    int tid = threadIdx.x;
    int lc = cnt[c];
    int n = lc < LIST_CAP ? lc : LIST_CAP;
    const int* list = lists + (long)c * LIST_CAP;
    int col = tid * 4;
    float a0 = 0.f, a1 = 0.f, a2 = 0.f, a3 = 0.f;
    for (int i = 0; i < n; ++i) {
        int2 w = *(const int2*)(tb + (long)list[i] * C_PAD + col);
        a0 += bf2f((short)(w.x & 0xffff));
        a1 += bf2f((short)(w.x >> 16));
        a2 += bf2f((short)(w.y & 0xffff));
        a3 += bf2f((short)(w.y >> 16));
    }
    short* o = Taggb + (long)c * C_PAD + col;
    o[0] = f2bf(a0); o[1] = f2bf(a1); o[2] = f2bf(a2); o[3] = f2bf(a3);
    if (tid == 0) {
        float s = 0.f;
        for (int i = 0; i < n; ++i) s += lse[list[i]];
        LS[c] = s;
        cntf[c] = (float)lc;
    }
}

// fused epilogue: bins scatter + final combine
__global__ __launch_bounds__(1024) void final2_k(
    const short* __restrict__ nkb, const int* __restrict__ labels,
    const float* __restrict__ dot, const float* __restrict__ pTagg,
    const float* __restrict__ ent, const float* __restrict__ cntf,
    const float* __restrict__ LS, const unsigned* __restrict__ mm,
    float* __restrict__ out)
{
    int n = blockIdx.x;
    int tid = threadIdx.x;
    __shared__ float bins[C_CLS];
    for (int c = tid; c < C_CLS; c += 1024) bins[c] = 0.f;
    __syncthreads();
    const short* row = nkb + (long)n * M_SUP;
    for (int m = tid * 2; m < M_SUP; m += 2048) {
        int w = *(const int*)(row + m);
        float v0 = bf2f((short)(w & 0xffff));
        float v1 = bf2f((short)(w >> 16));
        atomicAdd(&bins[labels[m]],     __expf(BETA_F * (v0 - 1.f)));
        atomicAdd(&bins[labels[m + 1]], __expf(BETA_F * (v1 - 1.f)));
    }
    __syncthreads();
    float klmin = decf(mm[0]), klmax = decf(mm[1]);
    float nkmin = decf(mm[2]), nkmax = decf(mm[3]);
    float ratio = (nkmax - nkmin) / (klmax - klmin);
    float e = ent[n];
    for (int c = tid; c < C_CLS; c += 1024) {
        float cc = cntf[c];
        float kls = cc * e - pTagg[(long)n * C_PAD + c] + LS[c];
        out[(long)n * C_CLS + c] = 100.f * dot[(long)n * C_PAD + c]
            - GAMMA_F * ((kls - cc * klmin) * ratio + cc * nkmin)
            + ALPHA_F * bins[c];
    }
}

// ---------- launch ----------
extern "C" void kernel_launch(void* const* d_in, const int* in_sizes, int n_in,
                              void* d_out, int out_size, void* d_ws, size_t ws_size,
                              hipStream_t stream) {
    const float* image_features = (const float*)d_in[0];   // [N, D]
    const float* text_embeds    = (const float*)d_in[1];   // [C, D]
    const float* support_feats  = (const float*)d_in[2];   // [D, M]
    const int*   support_labels = (const int*)d_in[3];     // [M]
    float* out = (float*)d_out;

    char* base = (char*)d_ws;
    size_t off = 0;
    auto alloc = [&](size_t bytes) {
        void* p = base + off;
        off = (off + bytes + 255) & ~(size_t)255;
        return p;
    };
    short* Tnb    = (short*)alloc(sizeof(short) * C_CLS * D_DIM);
    short* imgb   = (short*)alloc(sizeof(short) * N_IMG * D_DIM);
    short* Sb     = (short*)alloc(sizeof(short) * M_SUP * D_DIM);
    short* tb     = (short*)alloc(sizeof(short) * M_SUP * C_PAD);
    short* pb     = (short*)alloc(sizeof(short) * N_IMG * C_PAD);
    short* nkb    = (short*)alloc(sizeof(short) * N_IMG * M_SUP);  // [N x M]
    short* Taggb  = (short*)alloc(sizeof(short) * C_CLS * C_PAD);
    float* dot    = (float*)alloc(sizeof(float) * N_IMG * C_PAD);
    float* pTagg  = (float*)alloc(sizeof(float) * N_IMG * C_PAD);
    float* lsesum = (float*)alloc(sizeof(float) * M_SUP);
    float* lse    = (float*)alloc(sizeof(float) * M_SUP);
    float* ent    = (float*)alloc(sizeof(float) * N_IMG);
    float* cntf   = (float*)alloc(sizeof(float) * C_CLS);
    float* LS     = (float*)alloc(sizeof(float) * C_CLS);
    int*   cnt    = (int*)alloc(sizeof(int) * C_CLS);
    int*   lists  = (int*)alloc(sizeof(int) * C_CLS * LIST_CAP);
    unsigned* mm  = (unsigned*)alloc(256);

    hipMemsetAsync(lsesum, 0, sizeof(float) * M_SUP, stream);
    init_mm_k<<<1, 256, 0, stream>>>(mm, cnt);
    normalize_rows_k<<<C_CLS, 256, 0, stream>>>(text_embeds, Tnb);
    normalize_rows_k<<<N_IMG, 256, 0, stream>>>(image_features, imgb);
    transpose_bf16_k<<<dim3(M_SUP / 32, D_DIM / 32), 256, 0, stream>>>(support_feats, Sb);
    bucket_k<<<(M_SUP + 255) / 256, 256, 0, stream>>>(support_labels, cnt, lists);

    // GEMM1 fused with partial LSE (fixed shift 2: |t|<=2)
    gemm1_k<<<dim3(C_PAD / 256, M_SUP / 128), 256, 0, stream>>>(Sb, Tnb, tb, lsesum);
    lse_fin_k<<<(M_SUP + 255) / 256, 256, 0, stream>>>(lsesum, lse);

    // GEMM0: dot[n,c] = imgb[n,:] . Tnb[c,:]
    mfma_gemm<0><<<dim3(8, 4), 256, 0, stream>>>(
        imgb, Tnb, dot, N_IMG, C_CLS, C_PAD, D_DIM, D_DIM, D_DIM, C_PAD, 1.0f);

    test_softmax_k<<<N_IMG, 256, 0, stream>>>(dot, pb, ent);

    // Tagg[c,:] = sum_{label=c} tb[m,:]; LS, cnt
    tagg_k<<<C_CLS, 256, 0, stream>>>(tb, cnt, lists, lse, Taggb, cntf, LS);

    // pTagg[n,c] = pb[n,:] . Taggb[c,:]
    mfma_gemm<0><<<dim3(8, 4), 256, 0, stream>>>(
        pb, Taggb, pTagg, N_IMG, C_CLS, C_CLS, C_PAD, C_PAD, C_PAD, C_PAD, 1.0f);

    // GEMM2': kl minmax only — tb rows on grid.x, j split in 2
    tallgemm<2><<<dim3(M_SUP / 64, 2), 256, 0, stream>>>(
        tb, pb, nullptr, C_PAD, ent, lse, mm);

    // GEMM3': nk^T store into [N x M] bf16 + minmax
    tallgemm<3><<<dim3(M_SUP / 64, 2), 256, 0, stream>>>(
        Sb, imgb, nkb, D_DIM, nullptr, nullptr, mm);

    final2_k<<<N_IMG, 1024, 0, stream>>>(
        nkb, support_labels, dot, pTagg, ent, cntf, LS, mm, out);
}